// Round 1
// baseline (467.710 us; speedup 1.0000x reference)
//
#include <hip/hip_runtime.h>

// MMD loss, N=4096 per side, D=256, fp32.
// Phase 1: row squared norms + column sums -> analytic sum(L2) -> bandwidth scale.
// Phase 2: fused tiled Gram -> L2 -> sum_{i=0..4} exp(-L2/(bw*2^i)) -> signed reduce.
// Upper-triangular tiles only (weight 2 off-diagonal, 1 on diagonal).

#define NROWS 8192
#define HALF  4096
#define DIM   256
#define TILE  64
#define LSTR  68   // LDS row stride (floats): 68*4=272 B, multiple of 16 -> aligned b128

__device__ __forceinline__ const float* row_ptr(const float* src, const float* tgt, int r) {
    return (r < HALF) ? (src + (size_t)r * DIM) : (tgt + (size_t)(r - HALF) * DIM);
}

// --- Phase 1a: sq[i] = |row_i|^2 ; block 0 zeroes colsum + accum ---
__global__ __launch_bounds__(256) void k_rowsq(const float* __restrict__ src,
                                               const float* __restrict__ tgt,
                                               float* __restrict__ sq,
                                               float* __restrict__ colsum,
                                               double* __restrict__ accum) {
    int wave = threadIdx.x >> 6;
    int lane = threadIdx.x & 63;
    int row  = blockIdx.x * 4 + wave;
    const float* rp = row_ptr(src, tgt, row);
    float4 v = ((const float4*)rp)[lane];           // 64 lanes * 4 floats = 256
    float s = v.x * v.x + v.y * v.y + v.z * v.z + v.w * v.w;
    #pragma unroll
    for (int off = 32; off; off >>= 1) s += __shfl_xor(s, off, 64);
    if (lane == 0) sq[row] = s;
    if (blockIdx.x == 0) {
        colsum[threadIdx.x] = 0.0f;
        if (threadIdx.x == 0) *accum = 0.0;
    }
}

// --- Phase 1b: colsum[d] = sum_i total[i][d] ---
__global__ __launch_bounds__(256) void k_colsum(const float* __restrict__ src,
                                                const float* __restrict__ tgt,
                                                float* __restrict__ colsum) {
    int d  = threadIdx.x;
    int r0 = blockIdx.x * 32;
    float s = 0.0f;
    for (int r = r0; r < r0 + 32; ++r) {
        s += row_ptr(src, tgt, r)[d];               // coalesced across threads
    }
    atomicAdd(&colsum[d], s);
}

// --- Phase 1c: bandwidth -> exp2 scale factor ---
__global__ __launch_bounds__(256) void k_scale(const float* __restrict__ sq,
                                               const float* __restrict__ colsum,
                                               float* __restrict__ scale) {
    __shared__ double sh[256];
    int t = threadIdx.x;
    double s1 = 0.0;
    for (int i = t; i < NROWS; i += 256) s1 += (double)sq[i];
    sh[t] = s1;
    __syncthreads();
    for (int off = 128; off; off >>= 1) {
        if (t < off) sh[t] += sh[t + off];
        __syncthreads();
    }
    double S1 = sh[0];
    __syncthreads();
    double c = (double)colsum[t];
    sh[t] = c * c;
    __syncthreads();
    for (int off = 128; off; off >>= 1) {
        if (t < off) sh[t] += sh[t + off];
        __syncthreads();
    }
    if (t == 0) {
        double S2    = sh[0];
        double n     = (double)NROWS;
        double sumL2 = 2.0 * n * S1 - 2.0 * S2;
        double bw    = sumL2 / (n * n - n) / 4.0;   // / KERNEL_MUL^(KERNEL_NUM//2)
        // u = exp(-L2/(16*bw)) = exp2(scale * L2)
        *scale = (float)(-1.0 / (16.0 * bw * 0.69314718055994530942));
    }
}

// --- Phase 2: fused pair-tile kernel ---
__global__ __launch_bounds__(256) void k_pairs(const float* __restrict__ src,
                                               const float* __restrict__ tgt,
                                               const float* __restrict__ sq,
                                               const float* __restrict__ scale_p,
                                               double* __restrict__ accum) {
    int bi = blockIdx.y, bj = blockIdx.x;
    if (bj < bi) return;                            // upper-triangular tiles only

    __shared__ float As[TILE][LSTR];
    __shared__ float Bs[TILE][LSTR];
    __shared__ float wsum[4];

    int t  = threadIdx.x;
    int tx = t & 15, ty = t >> 4;
    int ro = bi * TILE, co = bj * TILE;
    const float* Ab = row_ptr(src, tgt, ro);        // tile never straddles the halves
    const float* Bb = row_ptr(src, tgt, co);

    float acc[4][4] = {};

    #pragma unroll
    for (int kk = 0; kk < DIM; kk += TILE) {
        __syncthreads();
        #pragma unroll
        for (int it = 0; it < 4; ++it) {
            int idx = t + it * 256;
            int r = idx >> 4, c4 = idx & 15;
            float4 va = *(const float4*)(Ab + r * DIM + kk + c4 * 4);
            float4 vb = *(const float4*)(Bb + r * DIM + kk + c4 * 4);
            *(float4*)&As[r][c4 * 4] = va;
            *(float4*)&Bs[r][c4 * 4] = vb;
        }
        __syncthreads();
        #pragma unroll
        for (int k = 0; k < TILE; k += 4) {
            float4 a[4], b[4];
            #pragma unroll
            for (int m = 0; m < 4; ++m) a[m] = *(const float4*)&As[ty * 4 + m][k];
            #pragma unroll
            for (int n = 0; n < 4; ++n) b[n] = *(const float4*)&Bs[tx * 4 + n][k];
            #pragma unroll
            for (int m = 0; m < 4; ++m)
                #pragma unroll
                for (int n = 0; n < 4; ++n)
                    acc[m][n] = fmaf(a[m].x, b[n].x,
                                fmaf(a[m].y, b[n].y,
                                fmaf(a[m].z, b[n].z,
                                fmaf(a[m].w, b[n].w, acc[m][n]))));
        }
    }

    float scale = *scale_p;
    float sqa[4], sqb[4];
    #pragma unroll
    for (int m = 0; m < 4; ++m) sqa[m] = sq[ro + ty * 4 + m];
    #pragma unroll
    for (int n = 0; n < 4; ++n) sqb[n] = sq[co + tx * 4 + n];

    float tsum = 0.0f;
    #pragma unroll
    for (int m = 0; m < 4; ++m) {
        #pragma unroll
        for (int n = 0; n < 4; ++n) {
            float L2  = sqa[m] + sqb[n] - 2.0f * acc[m][n];
            float u   = __builtin_amdgcn_exp2f(scale * L2);
            float u2  = u * u;
            float u4  = u2 * u2;
            float u8  = u4 * u4;
            float u16 = u8 * u8;
            tsum += u + u2 + u4 + u8 + u16;         // sum over the 5 kernel scales
        }
    }

    #pragma unroll
    for (int off = 32; off; off >>= 1) tsum += __shfl_xor(tsum, off, 64);
    if ((t & 63) == 0) wsum[t >> 6] = tsum;
    __syncthreads();
    if (t == 0) {
        float tot = wsum[0] + wsum[1] + wsum[2] + wsum[3];
        float sgn = ((ro < HALF) == (co < HALF)) ? 1.0f : -1.0f;
        float w   = (bi == bj) ? 1.0f : 2.0f;       // off-diag tiles stand for (i,j)+(j,i)
        atomicAdd(accum, (double)(sgn * w * tot));
    }
}

// --- Finalize: mean normalization ---
__global__ void k_fin(const double* __restrict__ accum, float* __restrict__ out) {
    out[0] = (float)(*accum / ((double)HALF * (double)HALF));
}

extern "C" void kernel_launch(void* const* d_in, const int* in_sizes, int n_in,
                              void* d_out, int out_size, void* d_ws, size_t ws_size,
                              hipStream_t stream) {
    const float* src = (const float*)d_in[0];
    const float* tgt = (const float*)d_in[1];
    float* out = (float*)d_out;

    char* ws = (char*)d_ws;
    double* accum  = (double*)ws;                   // 8 B
    float*  scale  = (float*)(ws + 8);              // 4 B
    float*  sq     = (float*)(ws + 64);             // 8192 floats
    float*  colsum = (float*)(ws + 64 + NROWS * 4); // 256 floats

    k_rowsq <<<NROWS / 4, 256, 0, stream>>>(src, tgt, sq, colsum, accum);
    k_colsum<<<NROWS / 32, 256, 0, stream>>>(src, tgt, colsum);
    k_scale <<<1, 256, 0, stream>>>(sq, colsum, scale);
    k_pairs <<<dim3(NROWS / TILE, NROWS / TILE), 256, 0, stream>>>(src, tgt, sq, scale, accum);
    k_fin   <<<1, 1, 0, stream>>>(accum, out);
}

// Round 2
// 392.307 us; speedup vs baseline: 1.1922x; 1.1922x over previous
//
#include <hip/hip_runtime.h>

// MMD loss, N=4096 per side, D=256, fp32.
// Phase 1: row squared norms + column sums -> analytic sum(L2) -> bandwidth scale.
// Phase 2: fused tiled Gram -> L2 -> sum_{i=0..4} exp(-L2/(bw*2^i)) -> signed reduce.
// R2: 128x128 tile, 8x8 acc/thread (1 B LDS per FMA -> VALU-bound), XOR-swizzled
//     LDS groups (16B granules, group ^= (row>>3)&7) -> B-reads 2-way (free),
//     A-reads broadcast. Upper-triangular tiles, weight 2 off-diagonal.

#define NROWS 8192
#define HALF  4096
#define DIM   256
#define BM    128
#define BK    32          // 8 float4 groups per row

__device__ __forceinline__ const float* row_ptr(const float* src, const float* tgt, int r) {
    return (r < HALF) ? (src + (size_t)r * DIM) : (tgt + (size_t)(r - HALF) * DIM);
}

// --- Phase 1a: sq[i] = |row_i|^2 ; block 0 zeroes colsum + accum ---
__global__ __launch_bounds__(256) void k_rowsq(const float* __restrict__ src,
                                               const float* __restrict__ tgt,
                                               float* __restrict__ sq,
                                               float* __restrict__ colsum,
                                               double* __restrict__ accum) {
    int wave = threadIdx.x >> 6;
    int lane = threadIdx.x & 63;
    int row  = blockIdx.x * 4 + wave;
    const float* rp = row_ptr(src, tgt, row);
    float4 v = ((const float4*)rp)[lane];           // 64 lanes * 4 floats = 256
    float s = v.x * v.x + v.y * v.y + v.z * v.z + v.w * v.w;
    #pragma unroll
    for (int off = 32; off; off >>= 1) s += __shfl_xor(s, off, 64);
    if (lane == 0) sq[row] = s;
    if (blockIdx.x == 0) {
        colsum[threadIdx.x] = 0.0f;
        if (threadIdx.x == 0) *accum = 0.0;
    }
}

// --- Phase 1b: colsum[d] = sum_i total[i][d] ---
__global__ __launch_bounds__(256) void k_colsum(const float* __restrict__ src,
                                                const float* __restrict__ tgt,
                                                float* __restrict__ colsum) {
    int d  = threadIdx.x;
    int r0 = blockIdx.x * 32;
    float s = 0.0f;
    for (int r = r0; r < r0 + 32; ++r) {
        s += row_ptr(src, tgt, r)[d];               // coalesced across threads
    }
    atomicAdd(&colsum[d], s);
}

// --- Phase 1c: bandwidth -> exp2 scale factor ---
__global__ __launch_bounds__(256) void k_scale(const float* __restrict__ sq,
                                               const float* __restrict__ colsum,
                                               float* __restrict__ scale) {
    __shared__ double sh[256];
    int t = threadIdx.x;
    double s1 = 0.0;
    for (int i = t; i < NROWS; i += 256) s1 += (double)sq[i];
    sh[t] = s1;
    __syncthreads();
    for (int off = 128; off; off >>= 1) {
        if (t < off) sh[t] += sh[t + off];
        __syncthreads();
    }
    double S1 = sh[0];
    __syncthreads();
    double c = (double)colsum[t];
    sh[t] = c * c;
    __syncthreads();
    for (int off = 128; off; off >>= 1) {
        if (t < off) sh[t] += sh[t + off];
        __syncthreads();
    }
    if (t == 0) {
        double S2    = sh[0];
        double n     = (double)NROWS;
        double sumL2 = 2.0 * n * S1 - 2.0 * S2;
        double bw    = sumL2 / (n * n - n) / 4.0;   // / KERNEL_MUL^(KERNEL_NUM//2)
        // u = exp(-L2/(16*bw)) = exp2(scale * L2)
        *scale = (float)(-1.0 / (16.0 * bw * 0.69314718055994530942));
    }
}

// --- Phase 2: fused pair-tile kernel, 128x128 tile, 8x8 per thread ---
__global__ __launch_bounds__(256, 3) void k_pairs(const float* __restrict__ src,
                                                  const float* __restrict__ tgt,
                                                  const float* __restrict__ sq,
                                                  const float* __restrict__ scale_p,
                                                  double* __restrict__ accum) {
    int bi = blockIdx.y, bj = blockIdx.x;
    if (bj < bi) return;                            // upper-triangular tiles only

    // Swizzled LDS: element (r, g*4+j) stored at [r*BK + (g ^ ((r>>3)&7))*4 + j]
    __shared__ float As[BM * BK];
    __shared__ float Bs[BM * BK];
    __shared__ float wsum[4];

    int t  = threadIdx.x;
    int tx = t & 15, ty = t >> 4;                   // 16x16 thread grid, 8x8 each
    int ro = bi * BM, co = bj * BM;
    const float* Ab = row_ptr(src, tgt, ro);        // tile never straddles the halves
    const float* Bb = row_ptr(src, tgt, co);

    float acc[8][8] = {};

    int sr = t >> 3;                                // staging: row (0..31 per it-step of 32)
    int sg = t & 7;                                 //          group within row
    for (int kk = 0; kk < DIM; kk += BK) {
        __syncthreads();
        #pragma unroll
        for (int it = 0; it < 4; ++it) {
            int r = sr + it * 32;
            int p = sg ^ ((r >> 3) & 7);
            float4 va = *(const float4*)(Ab + r * DIM + kk + sg * 4);
            float4 vb = *(const float4*)(Bb + r * DIM + kk + sg * 4);
            *(float4*)&As[r * BK + p * 4] = va;
            *(float4*)&Bs[r * BK + p * 4] = vb;
        }
        __syncthreads();
        #pragma unroll
        for (int kq = 0; kq < BK / 4; ++kq) {
            float4 a[8], b[8];
            int pa = (kq ^ (ty & 7)) * 4;
            int pb = (kq ^ (tx & 7)) * 4;
            #pragma unroll
            for (int m = 0; m < 8; ++m) a[m] = *(const float4*)&As[(ty * 8 + m) * BK + pa];
            #pragma unroll
            for (int n = 0; n < 8; ++n) b[n] = *(const float4*)&Bs[(tx * 8 + n) * BK + pb];
            #pragma unroll
            for (int m = 0; m < 8; ++m)
                #pragma unroll
                for (int n = 0; n < 8; ++n)
                    acc[m][n] = fmaf(a[m].x, b[n].x,
                                fmaf(a[m].y, b[n].y,
                                fmaf(a[m].z, b[n].z,
                                fmaf(a[m].w, b[n].w, acc[m][n]))));
        }
    }

    float scale = *scale_p;
    float sqa[8], sqb[8];
    #pragma unroll
    for (int m = 0; m < 8; ++m) sqa[m] = sq[ro + ty * 8 + m];
    #pragma unroll
    for (int n = 0; n < 8; ++n) sqb[n] = sq[co + tx * 8 + n];

    float tsum = 0.0f;
    #pragma unroll
    for (int m = 0; m < 8; ++m) {
        #pragma unroll
        for (int n = 0; n < 8; ++n) {
            float L2  = sqa[m] + sqb[n] - 2.0f * acc[m][n];
            float u   = __builtin_amdgcn_exp2f(scale * L2);
            float u2  = u * u;
            float u4  = u2 * u2;
            float u8  = u4 * u4;
            float u16 = u8 * u8;
            tsum += u + u2 + u4 + u8 + u16;         // sum over the 5 kernel scales
        }
    }

    #pragma unroll
    for (int off = 32; off; off >>= 1) tsum += __shfl_xor(tsum, off, 64);
    if ((t & 63) == 0) wsum[t >> 6] = tsum;
    __syncthreads();
    if (t == 0) {
        float tot = wsum[0] + wsum[1] + wsum[2] + wsum[3];
        float sgn = ((ro < HALF) == (co < HALF)) ? 1.0f : -1.0f;
        float w   = (bi == bj) ? 1.0f : 2.0f;       // off-diag tiles stand for (i,j)+(j,i)
        atomicAdd(accum, (double)(sgn * w * tot));
    }
}

// --- Finalize: mean normalization ---
__global__ void k_fin(const double* __restrict__ accum, float* __restrict__ out) {
    out[0] = (float)(*accum / ((double)HALF * (double)HALF));
}

extern "C" void kernel_launch(void* const* d_in, const int* in_sizes, int n_in,
                              void* d_out, int out_size, void* d_ws, size_t ws_size,
                              hipStream_t stream) {
    const float* src = (const float*)d_in[0];
    const float* tgt = (const float*)d_in[1];
    float* out = (float*)d_out;

    char* ws = (char*)d_ws;
    double* accum  = (double*)ws;                   // 8 B
    float*  scale  = (float*)(ws + 8);              // 4 B
    float*  sq     = (float*)(ws + 64);             // 8192 floats
    float*  colsum = (float*)(ws + 64 + NROWS * 4); // 256 floats

    k_rowsq <<<NROWS / 4, 256, 0, stream>>>(src, tgt, sq, colsum, accum);
    k_colsum<<<NROWS / 32, 256, 0, stream>>>(src, tgt, colsum);
    k_scale <<<1, 256, 0, stream>>>(sq, colsum, scale);
    k_pairs <<<dim3(NROWS / BM, NROWS / BM), 256, 0, stream>>>(src, tgt, sq, scale, accum);
    k_fin   <<<1, 1, 0, stream>>>(accum, out);
}

// Round 3
// 193.812 us; speedup vs baseline: 2.4132x; 2.0242x over previous
//
#include <hip/hip_runtime.h>

// MMD loss, N=4096 per side, D=256, fp32.
// R3: split-bf16 MFMA Gram. x = hi + lo (both bf16); dot = 4 MFMA passes
//     (hh + hl + lh + ll) into one fp32 accumulator -> ~2^-18 relative error.
//     128x128 tile, 4 waves in 2x2, each wave 4x4 subtiles of 16x16x32 MFMA.
//     In-kernel fp32->hi/lo conversion during staging (no big workspace).
//     Granule-XOR swizzle keeps LDS stores and frag reads bank-uniform.
//     Bandwidth scale from exact fp32 pre-pass (unchanged semantics).

#define NROWS 8192
#define HALF  4096
#define DIM   256
#define BM    128
#define BK    32          // = MFMA K; 4 granules of 8 bf16 per row

typedef __bf16 bf16x8 __attribute__((ext_vector_type(8)));
typedef float f32x4 __attribute__((ext_vector_type(4)));
typedef unsigned short ushort8 __attribute__((ext_vector_type(8)));

__device__ __forceinline__ const float* row_ptr(const float* src, const float* tgt, int r) {
    return (r < HALF) ? (src + (size_t)r * DIM) : (tgt + (size_t)(r - HALF) * DIM);
}

__device__ __forceinline__ unsigned short bf16_rne(float x) {
    unsigned int u = __builtin_bit_cast(unsigned int, x);
    return (unsigned short)((u + 0x7FFFu + ((u >> 16) & 1u)) >> 16);
}

// --- Phase 1a: sq[i] = |row_i|^2 ; block 0 zeroes colsum + accum ---
__global__ __launch_bounds__(256) void k_rowsq(const float* __restrict__ src,
                                               const float* __restrict__ tgt,
                                               float* __restrict__ sq,
                                               float* __restrict__ colsum,
                                               double* __restrict__ accum) {
    int wave = threadIdx.x >> 6;
    int lane = threadIdx.x & 63;
    int row  = blockIdx.x * 4 + wave;
    const float* rp = row_ptr(src, tgt, row);
    float4 v = ((const float4*)rp)[lane];           // 64 lanes * 4 floats = 256
    float s = v.x * v.x + v.y * v.y + v.z * v.z + v.w * v.w;
    #pragma unroll
    for (int off = 32; off; off >>= 1) s += __shfl_xor(s, off, 64);
    if (lane == 0) sq[row] = s;
    if (blockIdx.x == 0) {
        colsum[threadIdx.x] = 0.0f;
        if (threadIdx.x == 0) *accum = 0.0;
    }
}

// --- Phase 1b: colsum[d] = sum_i total[i][d] ---
__global__ __launch_bounds__(256) void k_colsum(const float* __restrict__ src,
                                                const float* __restrict__ tgt,
                                                float* __restrict__ colsum) {
    int d  = threadIdx.x;
    int r0 = blockIdx.x * 32;
    float s = 0.0f;
    for (int r = r0; r < r0 + 32; ++r) {
        s += row_ptr(src, tgt, r)[d];               // coalesced across threads
    }
    atomicAdd(&colsum[d], s);
}

// --- Phase 1c: bandwidth -> exp2 scale factor ---
__global__ __launch_bounds__(256) void k_scale(const float* __restrict__ sq,
                                               const float* __restrict__ colsum,
                                               float* __restrict__ scale) {
    __shared__ double sh[256];
    int t = threadIdx.x;
    double s1 = 0.0;
    for (int i = t; i < NROWS; i += 256) s1 += (double)sq[i];
    sh[t] = s1;
    __syncthreads();
    for (int off = 128; off; off >>= 1) {
        if (t < off) sh[t] += sh[t + off];
        __syncthreads();
    }
    double S1 = sh[0];
    __syncthreads();
    double c = (double)colsum[t];
    sh[t] = c * c;
    __syncthreads();
    for (int off = 128; off; off >>= 1) {
        if (t < off) sh[t] += sh[t + off];
        __syncthreads();
    }
    if (t == 0) {
        double S2    = sh[0];
        double n     = (double)NROWS;
        double sumL2 = 2.0 * n * S1 - 2.0 * S2;
        double bw    = sumL2 / (n * n - n) / 4.0;   // / KERNEL_MUL^(KERNEL_NUM//2)
        // u = exp(-L2/(16*bw)) = exp2(scale * L2)
        *scale = (float)(-1.0 / (16.0 * bw * 0.69314718055994530942));
    }
}

// --- Phase 2: split-bf16 MFMA pair-tile kernel ---
__global__ __launch_bounds__(256, 2) void k_pairs(const float* __restrict__ src,
                                                  const float* __restrict__ tgt,
                                                  const float* __restrict__ sq,
                                                  const float* __restrict__ scale_p,
                                                  double* __restrict__ accum) {
    int bi = blockIdx.y, bj = blockIdx.x;
    if (bj < bi) return;                            // upper-triangular tiles only

    // LDS: element (r, granule q of 8 bf16) at physical granule p = q ^ ((r>>1)&3)
    __shared__ __align__(16) unsigned short AsH[BM * BK];
    __shared__ __align__(16) unsigned short AsL[BM * BK];
    __shared__ __align__(16) unsigned short BsH[BM * BK];
    __shared__ __align__(16) unsigned short BsL[BM * BK];
    __shared__ float wsum[4];

    int t    = threadIdx.x;
    int lane = t & 63;
    int w    = t >> 6;
    int wr   = w >> 1, wc = w & 1;                  // 2x2 wave grid, 64x64 each
    int lr   = lane & 15, lq = lane >> 4;
    int ro = bi * BM, co = bj * BM;
    const float* Ab = row_ptr(src, tgt, ro);        // tile never straddles the halves
    const float* Bb = row_ptr(src, tgt, co);

    int sr = t >> 1;                                // staging: row 0..127
    int shf = t & 1;                                //          k-half (16 floats)
    const float* gA = Ab + sr * DIM + shf * 16;
    const float* gB = Bb + sr * DIM + shf * 16;
    int swz = (sr >> 1) & 3;

    f32x4 acc[4][4];
    #pragma unroll
    for (int m = 0; m < 4; ++m)
        #pragma unroll
        for (int n = 0; n < 4; ++n) acc[m][n] = (f32x4){0.f, 0.f, 0.f, 0.f};

    #pragma unroll 1
    for (int kk = 0; kk < DIM; kk += BK) {
        __syncthreads();
        // ---- stage: load 16 fp32 of A-row + 16 of B-row, split hi/lo, write 2 granules each
        float fa[16], fb[16];
        #pragma unroll
        for (int i = 0; i < 4; ++i) {
            float4 va = *(const float4*)(gA + kk + i * 4);
            float4 vb = *(const float4*)(gB + kk + i * 4);
            fa[i*4+0]=va.x; fa[i*4+1]=va.y; fa[i*4+2]=va.z; fa[i*4+3]=va.w;
            fb[i*4+0]=vb.x; fb[i*4+1]=vb.y; fb[i*4+2]=vb.z; fb[i*4+3]=vb.w;
        }
        #pragma unroll
        for (int g = 0; g < 2; ++g) {
            int p = (shf * 2 + g) ^ swz;            // physical granule
            int idx = sr * BK + p * 8;
            ushort8 ah, al, bh, bl;
            #pragma unroll
            for (int j = 0; j < 8; ++j) {
                float xa = fa[g * 8 + j];
                unsigned short ha = bf16_rne(xa);
                float xra = __builtin_bit_cast(float, (unsigned int)ha << 16);
                ah[j] = ha; al[j] = bf16_rne(xa - xra);
                float xb = fb[g * 8 + j];
                unsigned short hb = bf16_rne(xb);
                float xrb = __builtin_bit_cast(float, (unsigned int)hb << 16);
                bh[j] = hb; bl[j] = bf16_rne(xb - xrb);
            }
            *(ushort8*)&AsH[idx] = ah;
            *(ushort8*)&AsL[idx] = al;
            *(ushort8*)&BsH[idx] = bh;
            *(ushort8*)&BsL[idx] = bl;
        }
        __syncthreads();

        // ---- fragments + 4-pass MFMA
        bf16x8 aH[4], aL[4], bH[4], bL[4];
        #pragma unroll
        for (int m = 0; m < 4; ++m) {
            int ar = wr * 64 + m * 16 + lr;
            int p  = lq ^ ((ar >> 1) & 3);
            int idx = ar * BK + p * 8;
            aH[m] = __builtin_bit_cast(bf16x8, *(const ushort8*)&AsH[idx]);
            aL[m] = __builtin_bit_cast(bf16x8, *(const ushort8*)&AsL[idx]);
        }
        #pragma unroll
        for (int n = 0; n < 4; ++n) {
            int br = wc * 64 + n * 16 + lr;
            int p  = lq ^ ((br >> 1) & 3);
            int idx = br * BK + p * 8;
            bH[n] = __builtin_bit_cast(bf16x8, *(const ushort8*)&BsH[idx]);
            bL[n] = __builtin_bit_cast(bf16x8, *(const ushort8*)&BsL[idx]);
        }
        #pragma unroll
        for (int m = 0; m < 4; ++m)
            #pragma unroll
            for (int n = 0; n < 4; ++n) {
                acc[m][n] = __builtin_amdgcn_mfma_f32_16x16x32_bf16(aH[m], bH[n], acc[m][n], 0, 0, 0);
                acc[m][n] = __builtin_amdgcn_mfma_f32_16x16x32_bf16(aH[m], bL[n], acc[m][n], 0, 0, 0);
                acc[m][n] = __builtin_amdgcn_mfma_f32_16x16x32_bf16(aL[m], bH[n], acc[m][n], 0, 0, 0);
                acc[m][n] = __builtin_amdgcn_mfma_f32_16x16x32_bf16(aL[m], bL[n], acc[m][n], 0, 0, 0);
            }
    }

    // ---- epilogue: L2 -> sum of 5 Gaussian kernels -> reduce
    float scale = *scale_p;
    int ro_eff = ro + wr * 64, co_eff = co + wc * 64;
    float4 sqa4[4];
    float  sqbv[4];
    #pragma unroll
    for (int m = 0; m < 4; ++m) sqa4[m] = *(const float4*)&sq[ro_eff + m * 16 + lq * 4];
    #pragma unroll
    for (int n = 0; n < 4; ++n) sqbv[n] = sq[co_eff + n * 16 + lr];

    float tsum = 0.0f;
    #pragma unroll
    for (int m = 0; m < 4; ++m) {
        float sa[4] = {sqa4[m].x, sqa4[m].y, sqa4[m].z, sqa4[m].w};
        #pragma unroll
        for (int n = 0; n < 4; ++n) {
            #pragma unroll
            for (int r = 0; r < 4; ++r) {
                float L2  = sa[r] + sqbv[n] - 2.0f * acc[m][n][r];
                float u   = __builtin_amdgcn_exp2f(scale * L2);
                float u2  = u * u;
                float u4  = u2 * u2;
                float u8  = u4 * u4;
                float u16 = u8 * u8;
                tsum += u + u2 + u4 + u8 + u16;     // 5 kernel scales
            }
        }
    }

    #pragma unroll
    for (int off = 32; off; off >>= 1) tsum += __shfl_xor(tsum, off, 64);
    if (lane == 0) wsum[w] = tsum;
    __syncthreads();
    if (t == 0) {
        float tot = wsum[0] + wsum[1] + wsum[2] + wsum[3];
        float sgn = ((ro < HALF) == (co < HALF)) ? 1.0f : -1.0f;
        float wgt = (bi == bj) ? 1.0f : 2.0f;       // off-diag tiles stand for (i,j)+(j,i)
        atomicAdd(accum, (double)(sgn * wgt * tot));
    }
}

// --- Finalize: mean normalization ---
__global__ void k_fin(const double* __restrict__ accum, float* __restrict__ out) {
    out[0] = (float)(*accum / ((double)HALF * (double)HALF));
}

extern "C" void kernel_launch(void* const* d_in, const int* in_sizes, int n_in,
                              void* d_out, int out_size, void* d_ws, size_t ws_size,
                              hipStream_t stream) {
    const float* src = (const float*)d_in[0];
    const float* tgt = (const float*)d_in[1];
    float* out = (float*)d_out;

    char* ws = (char*)d_ws;
    double* accum  = (double*)ws;                   // 8 B
    float*  scale  = (float*)(ws + 8);              // 4 B
    float*  sq     = (float*)(ws + 64);             // 8192 floats
    float*  colsum = (float*)(ws + 64 + NROWS * 4); // 256 floats

    k_rowsq <<<NROWS / 4, 256, 0, stream>>>(src, tgt, sq, colsum, accum);
    k_colsum<<<NROWS / 32, 256, 0, stream>>>(src, tgt, colsum);
    k_scale <<<1, 256, 0, stream>>>(sq, colsum, scale);
    k_pairs <<<dim3(NROWS / BM, NROWS / BM), 256, 0, stream>>>(src, tgt, sq, scale, accum);
    k_fin   <<<1, 1, 0, stream>>>(accum, out);
}